// Round 7
// baseline (206.968 us; speedup 1.0000x reference)
//
#include <hip/hip_runtime.h>
#include <hip/hip_bf16.h>

// ---------------------------------------------------------------------------
// QLayer: per-type 2-layer MLP.
//   h   = relu(x_t @ W1_t + b1_t)       [16384x512]@[512x1024]   (x4 types)
//   out = h @ W2_t + b2_t, padded to 128 cols                    (x4 types)
// Round 7: 128x128 tiles, 4 waves, 64 KB LDS -> 2 blocks/CU. Cross-block
// overlap replaces in-block scheduling (r2-r6 all ~26% MfmaUtil at 1 blk/CU:
// whole-CU barrier stalls were the invariant). cvt_x fused into GEMM1 via
// reg-staged f32->bf16 A path (issue-early / write-late, T14).
// ---------------------------------------------------------------------------

typedef __attribute__((ext_vector_type(8))) short short8;
typedef __attribute__((ext_vector_type(4))) float f32x4;

#define NT 4
#define NNODE 16384
#define DIN 512
#define DH 1024
#define MAXO 128

static __device__ __forceinline__ ushort f2bf(float f) {
    __hip_bfloat16 h = __float2bfloat16(f);
    return *reinterpret_cast<ushort*>(&h);
}

static __device__ __forceinline__ short8 pack8(const float4 a, const float4 b) {
    union { short8 v; ushort u[8]; } r;
    r.u[0] = f2bf(a.x); r.u[1] = f2bf(a.y); r.u[2] = f2bf(a.z); r.u[3] = f2bf(a.w);
    r.u[4] = f2bf(b.x); r.u[5] = f2bf(b.y); r.u[6] = f2bf(b.z); r.u[7] = f2bf(b.w);
    return r.v;
}

#define GLD(gsrc, ldst)                                                        \
    __builtin_amdgcn_global_load_lds(                                          \
        (const __attribute__((address_space(1))) void*)(gsrc),                 \
        (__attribute__((address_space(3))) void*)(ldst), 16, 0, 0)

// --- weight transpose+convert: in fp32 [R][Cin] -> out bf16 [Cout][R] ------
__global__ __launch_bounds__(256) void cvt_w_t_kernel(
    const float* __restrict__ in, ushort* __restrict__ out,
    int R, int Cin, size_t in_tstride, size_t out_tstride) {
    __shared__ float tile[32][33];
    const int t = blockIdx.z;
    in += (size_t)t * in_tstride;
    out += (size_t)t * out_tstride;
    const int c0 = blockIdx.x * 32, r0 = blockIdx.y * 32;
    const int cx = threadIdx.x & 31;
    const int ry = threadIdx.x >> 5;   // 0..7
#pragma unroll
    for (int j = 0; j < 4; ++j) {
        int rr = ry + j * 8;
        int c = c0 + cx;
        tile[rr][cx] = (c < Cin) ? in[(size_t)(r0 + rr) * Cin + c] : 0.0f;
    }
    __syncthreads();
#pragma unroll
    for (int j = 0; j < 4; ++j) {
        int cc = ry + j * 8;
        out[(size_t)(c0 + cc) * R + r0 + cx] = f2bf(tile[cx][cc]);
    }
}

// --- b2 pad to [4][128] fp32 ----------------------------------------------
__global__ void pad_b2_kernel(const float* __restrict__ b0, const float* __restrict__ b1,
                              const float* __restrict__ b2, const float* __restrict__ b3,
                              float* __restrict__ out) {
    const int i = threadIdx.x;            // 0..511
    const int t = i >> 7, n = i & 127;
    const int sz[4] = {128, 96, 64, 32};
    const float* b = (t == 0) ? b0 : (t == 1) ? b1 : (t == 2) ? b2 : b3;
    out[i] = (n < sz[t]) ? b[n] : 0.0f;
}

// ---------------------------------------------------------------------------
// 128x128-tile bf16 MFMA GEMM, 1 barrier per K-tile, dbuf LDS (64 KB ->
// 2 blocks/CU). 256 threads = 4 waves (2x2), wave tile 64x64, BK=64.
// XOR swizzle both sides: byte(row,c16) = row*128 + ((c16*16)^((row&7)<<4)).
//
// A path:
//   AFP32=1: A is fp32 (the x inputs). Tile i+1's A is global-loaded to
//            regs at tile-i top (8x float4), converted+ds_written (swizzled
//            dst) after tile-i's MFMAs (issue-early/write-late).
//   AFP32=0: A is bf16 (H); staged via global_load_lds w16, pre-swizzled src.
// B path: always bf16 global_load_lds w16, pre-swizzled src.
// Per K-tile: {issue next A+B; 2x(8 ds_read_b128 + 16 MFMA);
//              [cvt+ds_write A]; vmcnt(0)+lgkmcnt(0); s_barrier}.
// MFMA operands swapped (D-row dim = n) -> vectorized epilogue stores.
// ---------------------------------------------------------------------------
template <bool AFP32, bool RELU, bool OUTBF16>
__global__ __launch_bounds__(256, 2) void gemm128(
    const void* __restrict__ A0, const void* __restrict__ A1,
    const void* __restrict__ A2, const void* __restrict__ A3,
    const ushort* __restrict__ Bbase, const float* __restrict__ biasbase,
    void* __restrict__ Cbase, int N, int K, int MT,
    size_t strideA, size_t strideB, size_t strideBias, size_t strideC) {
    constexpr int ABY = 128 * 64 * 2;  // 16 KB
    constexpr int BBY = 128 * 64 * 2;  // 16 KB
    constexpr int BUF = ABY + BBY;     // 32 KB
    __shared__ char lds[2 * BUF];      // 64 KB -> 2 blocks/CU

    // XCD-bijective block swizzle (grid % 8 == 0 by construction)
    const int cpx = gridDim.x >> 3;
    const int g = blockIdx.x;
    const int wg = (g & 7) * cpx + (g >> 3);
    const int NTL = N / 128;
    const int t = wg / (MT * NTL);
    const int rmn = wg % (MT * NTL);
    const int m0 = (rmn / NTL) * 128;
    const int n0 = (rmn % NTL) * 128;

    const float* Af = (const float*)((t == 0) ? A0 : (t == 1) ? A1
                                   : (t == 2) ? A2 : A3);        // AFP32
    const ushort* Ab = (const ushort*)A0 + (size_t)t * strideA;  // !AFP32
    const ushort* Bp = Bbase + (size_t)t * strideB;
    const float* bias = biasbase + (size_t)t * strideBias;

    const int tid = threadIdx.x;
    const int lane = tid & 63;
    const int w = tid >> 6;
    const int wm = w >> 1, wn = w & 1;     // 2x2 waves, 64x64 each
    const int lrow = lane & 15, lgrp = lane >> 4;

    // --- staging addresses: 4 chunks/thread each for A and B ---------------
    const float* af32src[4];               // AFP32: linear f32 src
    const ushort* abfsrc[4];               // !AFP32: pre-swizzled bf16 src
    const ushort* bsrc[4];
    int adst[4], bdst[4];                  // A dst swizzled (AFP32) / linear
#pragma unroll
    for (int j = 0; j < 4; ++j) {
        const int c = j * 256 + tid;       // chunk 0..1023
        const int r = c >> 3;              // row 0..127
        const int c8 = c & 7;
        const int cb = (c8 * 16) ^ ((r & 7) << 4);
        if (AFP32) {
            af32src[j] = Af + (size_t)(m0 + r) * K + c8 * 8;
            adst[j] = r * 128 + cb;        // swizzled byte dst for ds_write
        } else {
            abfsrc[j] = Ab + (size_t)(m0 + r) * K + (cb >> 1);
            adst[j] = c * 16;              // linear dst for global_load_lds
        }
        bsrc[j] = Bp + (size_t)(n0 + r) * K + (cb >> 1);
        bdst[j] = ABY + c * 16;
    }

    f32x4 acc[4][4] = {};
    const int NK = K / 64;
    float4 fa[4][2];                       // staged A f32 regs (AFP32)

    // --- prologue: stage tile 0 into buf 0 ---------------------------------
    if (AFP32) {
#pragma unroll
        for (int j = 0; j < 4; ++j) {
            fa[j][0] = *reinterpret_cast<const float4*>(af32src[j]);
            fa[j][1] = *reinterpret_cast<const float4*>(af32src[j] + 4);
        }
#pragma unroll
        for (int j = 0; j < 4; ++j) GLD(bsrc[j], lds + bdst[j]);
#pragma unroll
        for (int j = 0; j < 4; ++j)
            *reinterpret_cast<short8*>(lds + adst[j]) = pack8(fa[j][0], fa[j][1]);
    } else {
#pragma unroll
        for (int j = 0; j < 4; ++j) GLD(abfsrc[j], lds + adst[j]);
#pragma unroll
        for (int j = 0; j < 4; ++j) GLD(bsrc[j], lds + bdst[j]);
    }
    asm volatile("s_waitcnt vmcnt(0) lgkmcnt(0)" ::: "memory");
    __builtin_amdgcn_s_barrier();
    asm volatile("" ::: "memory");

    for (int i = 0; i < NK; ++i) {
        const char* cu_ = lds + (i & 1) * BUF;
        char* nx_ = lds + ((i + 1) & 1) * BUF;
        const int ktn = (i + 1) * 64;
        const bool st = (i + 1 < NK);

        if (st) {
            if (AFP32) {
#pragma unroll
                for (int j = 0; j < 4; ++j) {
                    fa[j][0] = *reinterpret_cast<const float4*>(af32src[j] + ktn);
                    fa[j][1] = *reinterpret_cast<const float4*>(af32src[j] + ktn + 4);
                }
            } else {
#pragma unroll
                for (int j = 0; j < 4; ++j) GLD(abfsrc[j] + ktn, nx_ + adst[j]);
            }
#pragma unroll
            for (int j = 0; j < 4; ++j) GLD(bsrc[j] + ktn, nx_ + bdst[j]);
        }

#pragma unroll
        for (int kkk = 0; kkk < 2; ++kkk) {
            short8 bfr[4], af[4];
#pragma unroll
            for (int ni = 0; ni < 4; ++ni) {
                const int br = wn * 64 + ni * 16 + lrow;
                const int kb = (kkk * 64 + lgrp * 16) ^ ((br & 7) << 4);
                bfr[ni] = *(const short8*)(cu_ + ABY + br * 128 + kb);
            }
#pragma unroll
            for (int ml = 0; ml < 4; ++ml) {
                const int ar = wm * 64 + ml * 16 + lrow;
                const int kb = (kkk * 64 + lgrp * 16) ^ ((ar & 7) << 4);
                af[ml] = *(const short8*)(cu_ + ar * 128 + kb);
            }
#pragma unroll
            for (int ml = 0; ml < 4; ++ml)
#pragma unroll
                for (int ni = 0; ni < 4; ++ni)
                    acc[ml][ni] = __builtin_amdgcn_mfma_f32_16x16x32_bf16(
                        bfr[ni], af[ml], acc[ml][ni], 0, 0, 0);
        }

        if (st) {
            if (AFP32) {
                // write-late: loads issued at tile top have landed under MFMA
#pragma unroll
                for (int j = 0; j < 4; ++j)
                    *reinterpret_cast<short8*>(nx_ + adst[j]) =
                        pack8(fa[j][0], fa[j][1]);
            }
            asm volatile("s_waitcnt vmcnt(0) lgkmcnt(0)" ::: "memory");
            __builtin_amdgcn_s_barrier();
            asm volatile("" ::: "memory");
        }
    }

    // --- epilogue (swapped operands): lane holds 4 consecutive n at reg r --
    // m = wmoff + mi*16 + lrow ; n = wnoff + ni*16 + lgrp*4 + r
    const int wnoff = n0 + wn * 64;
    const int wmoff = m0 + wm * 64;
#pragma unroll
    for (int ni = 0; ni < 4; ++ni) {
        const int ncol = wnoff + ni * 16 + lgrp * 4;
        const float4 bv = *reinterpret_cast<const float4*>(&bias[ncol]);
#pragma unroll
        for (int mi = 0; mi < 4; ++mi) {
            const int row = wmoff + mi * 16 + lrow;
            float v0 = acc[mi][ni][0] + bv.x;
            float v1 = acc[mi][ni][1] + bv.y;
            float v2 = acc[mi][ni][2] + bv.z;
            float v3 = acc[mi][ni][3] + bv.w;
            if (RELU) {
                v0 = fmaxf(v0, 0.0f); v1 = fmaxf(v1, 0.0f);
                v2 = fmaxf(v2, 0.0f); v3 = fmaxf(v3, 0.0f);
            }
            const size_t base = (size_t)t * strideC + (size_t)row * N + ncol;
            if (OUTBF16) {
                uint2 p;
                p.x = (uint)f2bf(v0) | ((uint)f2bf(v1) << 16);
                p.y = (uint)f2bf(v2) | ((uint)f2bf(v3) << 16);
                *reinterpret_cast<uint2*>(&((ushort*)Cbase)[base]) = p;
            } else {
                float4 p = {v0, v1, v2, v3};
                *reinterpret_cast<float4*>(&((float*)Cbase)[base]) = p;
            }
        }
    }
}

extern "C" void kernel_launch(void* const* d_in, const int* in_sizes, int n_in,
                              void* d_out, int out_size, void* d_ws, size_t ws_size,
                              hipStream_t stream) {
    const float* x0 = (const float*)d_in[0];
    const float* x1 = (const float*)d_in[1];
    const float* x2 = (const float*)d_in[2];
    const float* x3 = (const float*)d_in[3];
    // d_in[4] = node_type (unused: nodes are blocked by type already)
    const float* W1 = (const float*)d_in[5];
    const float* b1 = (const float*)d_in[6];
    const float* W2[4] = {(const float*)d_in[7], (const float*)d_in[9],
                          (const float*)d_in[11], (const float*)d_in[13]};
    const float* b2[4] = {(const float*)d_in[8], (const float*)d_in[10],
                          (const float*)d_in[12], (const float*)d_in[14]};

    // workspace layout (bytes):
    //   H    bf16 [4][16384][1024]  134217728
    //   W1T  bf16 [4][1024][512]      4194304
    //   W2T  bf16 [4][128][1024]      1048576
    //   b2p  f32  [4][128]                2048
    char* ws = (char*)d_ws;
    ushort* H   = (ushort*)ws;
    ushort* W1T = (ushort*)(ws + 134217728ull);
    ushort* W2T = (ushort*)(ws + 134217728ull + 4194304ull);
    float*  b2p = (float*)(ws + 134217728ull + 4194304ull + 1048576ull);

    // weight conversions (small)
    cvt_w_t_kernel<<<dim3(32, 16, 4), 256, 0, stream>>>(
        W1, W1T, DIN, DH, (size_t)DIN * DH, (size_t)DH * DIN);
    const int osz[4] = {128, 96, 64, 32};
    for (int t = 0; t < 4; ++t)
        cvt_w_t_kernel<<<dim3(4, 32, 1), 256, 0, stream>>>(
            W2[t], W2T + (size_t)t * MAXO * DH, DH, osz[t], 0, 0);
    pad_b2_kernel<<<1, 512, 0, stream>>>(b2[0], b2[1], b2[2], b2[3], b2p);

    // layer 1: H = relu(X @ W1 + b1), fused f32->bf16 A path, bf16 out
    // grid: 4 types x 128 m-tiles x 8 n-tiles = 4096 (n fastest: A L2 reuse)
    gemm128<true, true, true><<<4096, 256, 0, stream>>>(
        x0, x1, x2, x3, W1T, b1, H,
        DH, DIN, NNODE / 128,
        0, (size_t)DH * DIN, (size_t)DH, (size_t)NNODE * DH);

    // layer 2: out = H @ W2 + b2 (padded cols exactly 0), fp32 out
    // grid: 4 types x 128 m-tiles x 1 n-tile = 512
    gemm128<false, false, false><<<512, 256, 0, stream>>>(
        H, H, H, H, W2T, b2p, d_out,
        MAXO, DH, NNODE / 128,
        (size_t)NNODE * DH, (size_t)MAXO * DH, (size_t)MAXO,
        (size_t)NNODE * MAXO);
}

// Round 8
// 175.908 us; speedup vs baseline: 1.1766x; 1.1766x over previous
//
#include <hip/hip_runtime.h>
#include <hip/hip_bf16.h>

// ---------------------------------------------------------------------------
// QLayer: per-type 2-layer MLP.
//   h   = relu(x_t @ W1_t + b1_t)       [16384x512]@[512x1024]   (x4 types)
//   out = h @ W2_t + b2_t, padded to 128 cols                    (x4 types)
// Round 8: r6's best GEMM structure (256-tile, 8 waves, 1 barrier/K-tile,
// dbuf LDS, XOR swizzle, XCD swizzle) + fp32->bf16 X conversion fused into
// GEMM1's A path (reg-stage 8x float4 at tile top, pack+ds_write after the
// 2480-cyc MFMA block covers the load latency). cvt_x pass deleted.
// ---------------------------------------------------------------------------

typedef __attribute__((ext_vector_type(8))) short short8;
typedef __attribute__((ext_vector_type(4))) float f32x4;

#define NT 4
#define NNODE 16384
#define DIN 512
#define DH 1024
#define MAXO 128

static __device__ __forceinline__ ushort f2bf(float f) {
    __hip_bfloat16 h = __float2bfloat16(f);
    return *reinterpret_cast<ushort*>(&h);
}

static __device__ __forceinline__ short8 pack8(const float4 a, const float4 b) {
    union { short8 v; ushort u[8]; } r;
    r.u[0] = f2bf(a.x); r.u[1] = f2bf(a.y); r.u[2] = f2bf(a.z); r.u[3] = f2bf(a.w);
    r.u[4] = f2bf(b.x); r.u[5] = f2bf(b.y); r.u[6] = f2bf(b.z); r.u[7] = f2bf(b.w);
    return r.v;
}

#define GLD(gsrc, ldst)                                                        \
    __builtin_amdgcn_global_load_lds(                                          \
        (const __attribute__((address_space(1))) void*)(gsrc),                 \
        (__attribute__((address_space(3))) void*)(ldst), 16, 0, 0)

// --- weight transpose+convert: in fp32 [R][Cin] -> out bf16 [Cout][R] ------
__global__ __launch_bounds__(256) void cvt_w_t_kernel(
    const float* __restrict__ in, ushort* __restrict__ out,
    int R, int Cin, size_t in_tstride, size_t out_tstride) {
    __shared__ float tile[32][33];
    const int t = blockIdx.z;
    in += (size_t)t * in_tstride;
    out += (size_t)t * out_tstride;
    const int c0 = blockIdx.x * 32, r0 = blockIdx.y * 32;
    const int cx = threadIdx.x & 31;
    const int ry = threadIdx.x >> 5;   // 0..7
#pragma unroll
    for (int j = 0; j < 4; ++j) {
        int rr = ry + j * 8;
        int c = c0 + cx;
        tile[rr][cx] = (c < Cin) ? in[(size_t)(r0 + rr) * Cin + c] : 0.0f;
    }
    __syncthreads();
#pragma unroll
    for (int j = 0; j < 4; ++j) {
        int cc = ry + j * 8;
        out[(size_t)(c0 + cc) * R + r0 + cx] = f2bf(tile[cx][cc]);
    }
}

// --- b2 pad to [4][128] fp32 ----------------------------------------------
__global__ void pad_b2_kernel(const float* __restrict__ b0, const float* __restrict__ b1,
                              const float* __restrict__ b2, const float* __restrict__ b3,
                              float* __restrict__ out) {
    const int i = threadIdx.x;            // 0..511
    const int t = i >> 7, n = i & 127;
    const int sz[4] = {128, 96, 64, 32};
    const float* b = (t == 0) ? b0 : (t == 1) ? b1 : (t == 2) ? b2 : b3;
    out[i] = (n < sz[t]) ? b[n] : 0.0f;
}

// ---------------------------------------------------------------------------
// 1-barrier-per-tile 256-tile bf16 GEMM: C = A[M][K] * BT[N][K]^T + bias
// BM=256, BN in {256,128}, BK=64, 512 threads = 8 waves (WM=2, WN=4).
// Wave tile 128 x (BN/4). LDS: dbuf x (A 32KB + B), XOR-swizzle both sides:
// byte(row,col16) = row*128 + ((col16*16) ^ ((row&7)<<4)).
//
// A path:
//   AFP32=1: A is fp32 (x inputs). Tile i+1's A is global-loaded to regs at
//            tile-i top (8x float4/thread), converted + ds_write_b128 to the
//            swizzled dst AFTER tile-i's MFMAs (issue-early / write-late;
//            the ~2480-cyc MFMA block covers the load latency).
//   AFP32=0: A is bf16 (H); global_load_lds w16, pre-swizzled src.
// B path: always bf16 global_load_lds w16, pre-swizzled src, linear dst.
// Per K-tile: {issue next A+B; 2x(frag ds_reads + 8*NF MFMA);
//              [pack+ds_write A]; vmcnt(0)+lgkmcnt(0); s_barrier}.
// MFMA operands swapped (D-row dim = n) -> vectorized epilogue stores.
// ---------------------------------------------------------------------------
template <int BN, bool AFP32, bool RELU, bool OUTBF16>
__global__ __launch_bounds__(512, 1) void gemmf(
    const void* __restrict__ A0, const void* __restrict__ A1,
    const void* __restrict__ A2, const void* __restrict__ A3,
    const ushort* __restrict__ Bbase, const float* __restrict__ biasbase,
    void* __restrict__ Cbase, int N, int K, int MT,
    size_t strideA, size_t strideB, size_t strideBias, size_t strideC) {
    constexpr int NF = BN / 64;            // N-frags per wave (4 or 2)
    constexpr int NBC = BN * 8 / 512;      // B chunks per thread (4 or 2)
    constexpr int ABYTES = 256 * 64 * 2;   // 32 KB
    constexpr int BBYTES = BN * 64 * 2;    // 32 or 16 KB
    constexpr int BUF = ABYTES + BBYTES;
    __shared__ char lds[2 * BUF];

    // XCD-bijective block swizzle (grid % 8 == 0 by construction)
    const int cpx = gridDim.x >> 3;
    const int g = blockIdx.x;
    const int wg = (g & 7) * cpx + (g >> 3);
    const int NTL = N / BN;
    const int t = wg / (MT * NTL);
    const int rmn = wg % (MT * NTL);
    const int m0 = (rmn / NTL) * 256;
    const int n0 = (rmn % NTL) * BN;

    const float* Af = (const float*)((t == 0) ? A0 : (t == 1) ? A1
                                   : (t == 2) ? A2 : A3);        // AFP32
    const ushort* Ab = (const ushort*)A0 + (size_t)t * strideA;  // !AFP32
    const ushort* Bp = Bbase + (size_t)t * strideB;
    const float* bias = biasbase + (size_t)t * strideBias;

    const int tid = threadIdx.x;
    const int lane = tid & 63;
    const int w = tid >> 6;
    const int wm = w >> 2, wn = w & 3;     // WM=2, WN=4
    const int lrow = lane & 15, lgrp = lane >> 4;

    // --- staging addresses: 4 A chunks + NBC B chunks per thread -----------
    const float* af32src[4];               // AFP32: linear f32 src
    const ushort* abfsrc[4];               // !AFP32: pre-swizzled bf16 src
    int adst[4];                           // AFP32: swizzled byte dst; else linear
#pragma unroll
    for (int j = 0; j < 4; ++j) {
        const int c = j * 512 + tid;       // chunk 0..2047
        const int r = c >> 3;              // A row 0..255
        const int c8 = c & 7;
        const int cb = (c8 * 16) ^ ((r & 7) << 4);
        if (AFP32) {
            af32src[j] = Af + (size_t)(m0 + r) * K + c8 * 8;
            adst[j] = r * 128 + cb;        // swizzled dst for ds_write_b128
        } else {
            abfsrc[j] = Ab + (size_t)(m0 + r) * K + (cb >> 1);
            adst[j] = c * 16;              // linear dst for global_load_lds
        }
    }
    const ushort* bsrc[NBC];
    int bdst[NBC];
#pragma unroll
    for (int j = 0; j < NBC; ++j) {
        const int c = j * 512 + tid;       // chunk 0..BN*8-1
        const int r = c >> 3;              // B row 0..BN-1
        const int cb = ((c & 7) * 16) ^ ((r & 7) << 4);
        bsrc[j] = Bp + (size_t)(n0 + r) * K + (cb >> 1);
        bdst[j] = ABYTES + c * 16;
    }

    f32x4 acc[8][NF] = {};
    const int NK = K / 64;
    float4 fa[4][2];                       // staged fp32 A regs (AFP32 path)

    // --- prologue: stage tile 0 into buf 0 ---------------------------------
    if (AFP32) {
#pragma unroll
        for (int j = 0; j < 4; ++j) {
            fa[j][0] = *reinterpret_cast<const float4*>(af32src[j]);
            fa[j][1] = *reinterpret_cast<const float4*>(af32src[j] + 4);
        }
#pragma unroll
        for (int j = 0; j < NBC; ++j) GLD(bsrc[j], lds + bdst[j]);
#pragma unroll
        for (int j = 0; j < 4; ++j)
            *reinterpret_cast<short8*>(lds + adst[j]) = pack8(fa[j][0], fa[j][1]);
    } else {
#pragma unroll
        for (int j = 0; j < 4; ++j) GLD(abfsrc[j], lds + adst[j]);
#pragma unroll
        for (int j = 0; j < NBC; ++j) GLD(bsrc[j], lds + bdst[j]);
    }
    asm volatile("s_waitcnt vmcnt(0) lgkmcnt(0)" ::: "memory");
    __builtin_amdgcn_s_barrier();
    asm volatile("" ::: "memory");

    for (int i = 0; i < NK; ++i) {
        const char* cu_ = lds + (i & 1) * BUF;
        char* nx_ = lds + ((i + 1) & 1) * BUF;
        const int ktn = (i + 1) * 64;
        const bool st = (i + 1 < NK);

        if (st) {
            if (AFP32) {
                // issue-early: fp32 A loads for tile i+1 (retire under MFMA)
#pragma unroll
                for (int j = 0; j < 4; ++j) {
                    fa[j][0] = *reinterpret_cast<const float4*>(af32src[j] + ktn);
                    fa[j][1] = *reinterpret_cast<const float4*>(af32src[j] + ktn + 4);
                }
            } else {
#pragma unroll
                for (int j = 0; j < 4; ++j) GLD(abfsrc[j] + ktn, nx_ + adst[j]);
            }
#pragma unroll
            for (int j = 0; j < NBC; ++j) GLD(bsrc[j] + ktn, nx_ + bdst[j]);
        }

#pragma unroll
        for (int kkk = 0; kkk < 2; ++kkk) {
            short8 bfr[NF], af[8];
#pragma unroll
            for (int ni = 0; ni < NF; ++ni) {
                const int br = wn * (NF * 16) + ni * 16 + lrow;
                const int kb = (kkk * 64 + lgrp * 16) ^ ((br & 7) << 4);
                bfr[ni] = *(const short8*)(cu_ + ABYTES + br * 128 + kb);
            }
#pragma unroll
            for (int ml = 0; ml < 8; ++ml) {
                const int ar = wm * 128 + ml * 16 + lrow;
                const int kb = (kkk * 64 + lgrp * 16) ^ ((ar & 7) << 4);
                af[ml] = *(const short8*)(cu_ + ar * 128 + kb);
            }
#pragma unroll
            for (int ml = 0; ml < 8; ++ml)
#pragma unroll
                for (int ni = 0; ni < NF; ++ni)
                    acc[ml][ni] = __builtin_amdgcn_mfma_f32_16x16x32_bf16(
                        bfr[ni], af[ml], acc[ml][ni], 0, 0, 0);
        }

        if (st) {
            if (AFP32) {
                // write-late: fa has landed under the MFMA block
#pragma unroll
                for (int j = 0; j < 4; ++j)
                    *reinterpret_cast<short8*>(nx_ + adst[j]) =
                        pack8(fa[j][0], fa[j][1]);
            }
            asm volatile("s_waitcnt vmcnt(0) lgkmcnt(0)" ::: "memory");
            __builtin_amdgcn_s_barrier();
            asm volatile("" ::: "memory");
        }
    }

    // --- epilogue (swapped operands): lane holds 4 consecutive n at reg r --
    // m = wmoff + mi*16 + lrow ; n = wnoff + ni*16 + lgrp*4 + r
    const int wnoff = n0 + wn * (NF * 16);
    const int wmoff = m0 + wm * 128;
#pragma unroll
    for (int ni = 0; ni < NF; ++ni) {
        const int ncol = wnoff + ni * 16 + lgrp * 4;
        const float4 bv = *reinterpret_cast<const float4*>(&bias[ncol]);
#pragma unroll
        for (int mi = 0; mi < 8; ++mi) {
            const int row = wmoff + mi * 16 + lrow;
            float v0 = acc[mi][ni][0] + bv.x;
            float v1 = acc[mi][ni][1] + bv.y;
            float v2 = acc[mi][ni][2] + bv.z;
            float v3 = acc[mi][ni][3] + bv.w;
            if (RELU) {
                v0 = fmaxf(v0, 0.0f); v1 = fmaxf(v1, 0.0f);
                v2 = fmaxf(v2, 0.0f); v3 = fmaxf(v3, 0.0f);
            }
            const size_t base = (size_t)t * strideC + (size_t)row * N + ncol;
            if (OUTBF16) {
                uint2 p;
                p.x = (uint)f2bf(v0) | ((uint)f2bf(v1) << 16);
                p.y = (uint)f2bf(v2) | ((uint)f2bf(v3) << 16);
                *reinterpret_cast<uint2*>(&((ushort*)Cbase)[base]) = p;
            } else {
                float4 p = {v0, v1, v2, v3};
                *reinterpret_cast<float4*>(&((float*)Cbase)[base]) = p;
            }
        }
    }
}

extern "C" void kernel_launch(void* const* d_in, const int* in_sizes, int n_in,
                              void* d_out, int out_size, void* d_ws, size_t ws_size,
                              hipStream_t stream) {
    const float* x0 = (const float*)d_in[0];
    const float* x1 = (const float*)d_in[1];
    const float* x2 = (const float*)d_in[2];
    const float* x3 = (const float*)d_in[3];
    // d_in[4] = node_type (unused: nodes are blocked by type already)
    const float* W1 = (const float*)d_in[5];
    const float* b1 = (const float*)d_in[6];
    const float* W2[4] = {(const float*)d_in[7], (const float*)d_in[9],
                          (const float*)d_in[11], (const float*)d_in[13]};
    const float* b2[4] = {(const float*)d_in[8], (const float*)d_in[10],
                          (const float*)d_in[12], (const float*)d_in[14]};

    // workspace layout (bytes):
    //   H    bf16 [4][16384][1024]  134217728
    //   W1T  bf16 [4][1024][512]      4194304
    //   W2T  bf16 [4][128][1024]      1048576
    //   b2p  f32  [4][128]                2048
    char* ws = (char*)d_ws;
    ushort* H   = (ushort*)ws;
    ushort* W1T = (ushort*)(ws + 134217728ull);
    ushort* W2T = (ushort*)(ws + 134217728ull + 4194304ull);
    float*  b2p = (float*)(ws + 134217728ull + 4194304ull + 1048576ull);

    // weight conversions (small)
    cvt_w_t_kernel<<<dim3(32, 16, 4), 256, 0, stream>>>(
        W1, W1T, DIN, DH, (size_t)DIN * DH, (size_t)DH * DIN);
    const int osz[4] = {128, 96, 64, 32};
    for (int t = 0; t < 4; ++t)
        cvt_w_t_kernel<<<dim3(4, 32, 1), 256, 0, stream>>>(
            W2[t], W2T + (size_t)t * MAXO * DH, DH, osz[t], 0, 0);
    pad_b2_kernel<<<1, 512, 0, stream>>>(b2[0], b2[1], b2[2], b2[3], b2p);

    // layer 1: H = relu(X @ W1 + b1), fused fp32->bf16 A path, bf16 out
    // grid: 4 types x 64 m-tiles x 4 n-tiles = 1024 (n fastest: A L2 reuse)
    gemmf<256, true, true, true><<<1024, 512, 0, stream>>>(
        x0, x1, x2, x3, W1T, b1, H,
        DH, DIN, NNODE / 256,
        0, (size_t)DH * DIN, (size_t)DH, (size_t)NNODE * DH);

    // layer 2: out = H @ W2 + b2 (padded cols exactly 0), fp32 out
    // grid: 4 types x 64 m-tiles x 1 n-tile = 256
    gemmf<128, false, false, false><<<256, 512, 0, stream>>>(
        H, H, H, H, W2T, b2p, d_out,
        MAXO, DH, NNODE / 256,
        (size_t)NNODE * DH, (size_t)MAXO * DH, (size_t)MAXO,
        (size_t)NNODE * MAXO);
}

// Round 9
// 153.409 us; speedup vs baseline: 1.3491x; 1.1467x over previous
//
#include <hip/hip_runtime.h>
#include <hip/hip_bf16.h>

// ---------------------------------------------------------------------------
// QLayer: per-type 2-layer MLP.
//   h   = relu(x_t @ W1_t + b1_t)       [16384x512]@[512x1024]   (x4 types)
//   out = h @ W2_t + b2_t, padded to 128 cols                    (x4 types)
// Round 9: fused fp32->bf16 A path pipelined ONE TILE DEEPER: fa regs hold
// tile i+1's X during tile i; ds_write at tile TOP (overlaps frag reads),
// refill loads get 2 tiles of latency; end-of-tile wait = vmcnt(8) (retires
// B only, fa loads stay in flight - T4). W2 conversions merged to 1 launch.
// ---------------------------------------------------------------------------

typedef __attribute__((ext_vector_type(8))) short short8;
typedef __attribute__((ext_vector_type(4))) float f32x4;

#define NT 4
#define NNODE 16384
#define DIN 512
#define DH 1024
#define MAXO 128

static __device__ __forceinline__ ushort f2bf(float f) {
    __hip_bfloat16 h = __float2bfloat16(f);
    return *reinterpret_cast<ushort*>(&h);
}

static __device__ __forceinline__ short8 pack8(const float4 a, const float4 b) {
    union { short8 v; ushort u[8]; } r;
    r.u[0] = f2bf(a.x); r.u[1] = f2bf(a.y); r.u[2] = f2bf(a.z); r.u[3] = f2bf(a.w);
    r.u[4] = f2bf(b.x); r.u[5] = f2bf(b.y); r.u[6] = f2bf(b.z); r.u[7] = f2bf(b.w);
    return r.v;
}

#define GLD(gsrc, ldst)                                                        \
    __builtin_amdgcn_global_load_lds(                                          \
        (const __attribute__((address_space(1))) void*)(gsrc),                 \
        (__attribute__((address_space(3))) void*)(ldst), 16, 0, 0)

// --- W1 transpose+convert: in fp32 [R][Cin] -> out bf16 [Cout][R] ----------
__global__ __launch_bounds__(256) void cvt_w_t_kernel(
    const float* __restrict__ in, ushort* __restrict__ out,
    int R, int Cin, size_t in_tstride, size_t out_tstride) {
    __shared__ float tile[32][33];
    const int t = blockIdx.z;
    in += (size_t)t * in_tstride;
    out += (size_t)t * out_tstride;
    const int c0 = blockIdx.x * 32, r0 = blockIdx.y * 32;
    const int cx = threadIdx.x & 31;
    const int ry = threadIdx.x >> 5;   // 0..7
#pragma unroll
    for (int j = 0; j < 4; ++j) {
        int rr = ry + j * 8;
        int c = c0 + cx;
        tile[rr][cx] = (c < Cin) ? in[(size_t)(r0 + rr) * Cin + c] : 0.0f;
    }
    __syncthreads();
#pragma unroll
    for (int j = 0; j < 4; ++j) {
        int cc = ry + j * 8;
        out[(size_t)(c0 + cc) * R + r0 + cx] = f2bf(tile[cx][cc]);
    }
}

// --- W2 (all 4 types) transpose+convert + b2 pad, one launch ---------------
// grid: (4, 32, 4); per t: in fp32 [DH][osz_t] -> out bf16 [128][DH] (rows
// >= osz_t are zero); block (0,0,t) threads 0..127 also pad b2.
__global__ __launch_bounds__(256) void cvt_w2_kernel(
    const float* __restrict__ w0, const float* __restrict__ w1,
    const float* __restrict__ w2, const float* __restrict__ w3,
    const float* __restrict__ c0_, const float* __restrict__ c1_,
    const float* __restrict__ c2_, const float* __restrict__ c3_,
    ushort* __restrict__ out, float* __restrict__ b2p) {
    __shared__ float tile[32][33];
    const int t = blockIdx.z;
    const int Cin = (t == 0) ? 128 : (t == 1) ? 96 : (t == 2) ? 64 : 32;
    const float* in = (t == 0) ? w0 : (t == 1) ? w1 : (t == 2) ? w2 : w3;
    ushort* o = out + (size_t)t * MAXO * DH;
    const int c0 = blockIdx.x * 32, r0 = blockIdx.y * 32;
    const int cx = threadIdx.x & 31;
    const int ry = threadIdx.x >> 5;
#pragma unroll
    for (int j = 0; j < 4; ++j) {
        int rr = ry + j * 8;
        int c = c0 + cx;
        tile[rr][cx] = (c < Cin) ? in[(size_t)(r0 + rr) * Cin + c] : 0.0f;
    }
    __syncthreads();
#pragma unroll
    for (int j = 0; j < 4; ++j) {
        int cc = ry + j * 8;
        o[(size_t)(c0 + cc) * DH + r0 + cx] = f2bf(tile[cx][cc]);
    }
    if (blockIdx.x == 0 && blockIdx.y == 0 && threadIdx.x < 128) {
        const float* b = (t == 0) ? c0_ : (t == 1) ? c1_ : (t == 2) ? c2_ : c3_;
        const int n = threadIdx.x;
        b2p[t * 128 + n] = (n < Cin) ? b[n] : 0.0f;
    }
}

// ---------------------------------------------------------------------------
// 1-barrier-per-tile 256-tile bf16 GEMM: C = A[M][K] * BT[N][K]^T + bias
// BM=256, BN in {256,128}, BK=64, 512 threads = 8 waves (WM=2, WN=4).
// Wave tile 128 x (BN/4). LDS: dbuf x (A 32KB + B), XOR-swizzle both sides:
// byte(row,col16) = row*128 + ((col16*16) ^ ((row&7)<<4)).
//
// A path, AFP32=1 (x inputs, fused fp32->bf16), 1-tile-deep reg pipeline:
//   invariant: entering tile i, fa regs hold X data of K-tile i+1.
//   tile top: [B GLDs (oldest)] [pack8+ds_write fa -> next buf]
//             [refill fa with tile i+2 (newest, 2 tiles to land)]
//   tile end: s_waitcnt vmcnt(8) (retire B; fa stays in flight) lgkmcnt(0).
// A path, AFP32=0 (H bf16): global_load_lds w16, pre-swizzled src.
// B path: always bf16 global_load_lds w16, pre-swizzled src, linear dst.
// MFMA operands swapped (D-row dim = n) -> vectorized epilogue stores.
// ---------------------------------------------------------------------------
template <int BN, bool AFP32, bool RELU, bool OUTBF16>
__global__ __launch_bounds__(512, 1) void gemmf(
    const void* __restrict__ A0, const void* __restrict__ A1,
    const void* __restrict__ A2, const void* __restrict__ A3,
    const ushort* __restrict__ Bbase, const float* __restrict__ biasbase,
    void* __restrict__ Cbase, int N, int K, int MT,
    size_t strideA, size_t strideB, size_t strideBias, size_t strideC) {
    constexpr int NF = BN / 64;            // N-frags per wave (4 or 2)
    constexpr int NBC = BN * 8 / 512;      // B chunks per thread (4 or 2)
    constexpr int ABYTES = 256 * 64 * 2;   // 32 KB
    constexpr int BBYTES = BN * 64 * 2;    // 32 or 16 KB
    constexpr int BUF = ABYTES + BBYTES;
    __shared__ char lds[2 * BUF];
    static_assert(!AFP32 || NBC == 4, "AFP32 path assumes BN=256");

    // XCD-bijective block swizzle (grid % 8 == 0 by construction)
    const int cpx = gridDim.x >> 3;
    const int g = blockIdx.x;
    const int wg = (g & 7) * cpx + (g >> 3);
    const int NTL = N / BN;
    const int t = wg / (MT * NTL);
    const int rmn = wg % (MT * NTL);
    const int m0 = (rmn / NTL) * 256;
    const int n0 = (rmn % NTL) * BN;

    const float* Af = (const float*)((t == 0) ? A0 : (t == 1) ? A1
                                   : (t == 2) ? A2 : A3);        // AFP32
    const ushort* Ab = (const ushort*)A0 + (size_t)t * strideA;  // !AFP32
    const ushort* Bp = Bbase + (size_t)t * strideB;
    const float* bias = biasbase + (size_t)t * strideBias;

    const int tid = threadIdx.x;
    const int lane = tid & 63;
    const int w = tid >> 6;
    const int wm = w >> 2, wn = w & 3;     // WM=2, WN=4
    const int lrow = lane & 15, lgrp = lane >> 4;

    // --- staging addresses: 4 A chunks + NBC B chunks per thread -----------
    const float* af32src[4];               // AFP32: linear f32 src
    const ushort* abfsrc[4];               // !AFP32: pre-swizzled bf16 src
    int adst[4];                           // AFP32: swizzled dst; else linear
#pragma unroll
    for (int j = 0; j < 4; ++j) {
        const int c = j * 512 + tid;       // chunk 0..2047
        const int r = c >> 3;              // A row 0..255
        const int c8 = c & 7;
        const int cb = (c8 * 16) ^ ((r & 7) << 4);
        if (AFP32) {
            af32src[j] = Af + (size_t)(m0 + r) * K + c8 * 8;
            adst[j] = r * 128 + cb;        // swizzled dst for ds_write_b128
        } else {
            abfsrc[j] = Ab + (size_t)(m0 + r) * K + (cb >> 1);
            adst[j] = c * 16;              // linear dst for global_load_lds
        }
    }
    const ushort* bsrc[NBC];
    int bdst[NBC];
#pragma unroll
    for (int j = 0; j < NBC; ++j) {
        const int c = j * 512 + tid;       // chunk 0..BN*8-1
        const int r = c >> 3;              // B row 0..BN-1
        const int cb = ((c & 7) * 16) ^ ((r & 7) << 4);
        bsrc[j] = Bp + (size_t)(n0 + r) * K + (cb >> 1);
        bdst[j] = ABYTES + c * 16;
    }

    f32x4 acc[8][NF] = {};
    const int NK = K / 64;
    float4 fa[4][2];                       // fp32 A regs (AFP32 path)

    // --- prologue ----------------------------------------------------------
    if (AFP32) {
        // fa <- tile 0
#pragma unroll
        for (int j = 0; j < 4; ++j) {
            fa[j][0] = *reinterpret_cast<const float4*>(af32src[j]);
            fa[j][1] = *reinterpret_cast<const float4*>(af32src[j] + 4);
        }
#pragma unroll
        for (int j = 0; j < NBC; ++j) GLD(bsrc[j], lds + bdst[j]);
        asm volatile("s_waitcnt vmcnt(4)" ::: "memory");   // fa0 landed
#pragma unroll
        for (int j = 0; j < 4; ++j)
            *reinterpret_cast<short8*>(lds + adst[j]) = pack8(fa[j][0], fa[j][1]);
        asm volatile("" ::: "memory");
        if (NK > 1) {
            // fa <- tile 1 (entering loop, fa holds tile i+1 = 1)
#pragma unroll
            for (int j = 0; j < 4; ++j) {
                fa[j][0] = *reinterpret_cast<const float4*>(af32src[j] + 64);
                fa[j][1] = *reinterpret_cast<const float4*>(af32src[j] + 68);
            }
        }
        asm volatile("s_waitcnt vmcnt(8) lgkmcnt(0)" ::: "memory"); // B0 done
    } else {
#pragma unroll
        for (int j = 0; j < 4; ++j) GLD(abfsrc[j], lds + adst[j]);
#pragma unroll
        for (int j = 0; j < NBC; ++j) GLD(bsrc[j], lds + bdst[j]);
        asm volatile("s_waitcnt vmcnt(0) lgkmcnt(0)" ::: "memory");
    }
    __builtin_amdgcn_s_barrier();
    asm volatile("" ::: "memory");

    for (int i = 0; i < NK; ++i) {
        const char* cu_ = lds + (i & 1) * BUF;
        char* nx_ = lds + ((i + 1) & 1) * BUF;
        const int ktn = (i + 1) * 64;
        const bool st = (i + 1 < NK);
        const bool st2 = (i + 2 < NK);

        if (st) {
#pragma unroll
            for (int j = 0; j < NBC; ++j) GLD(bsrc[j] + ktn, nx_ + bdst[j]);
            if (AFP32) {
                // publish fa (tile i+1 data, loaded a full tile ago)
#pragma unroll
                for (int j = 0; j < 4; ++j)
                    *reinterpret_cast<short8*>(nx_ + adst[j]) =
                        pack8(fa[j][0], fa[j][1]);
                asm volatile("" ::: "memory");   // keep refill below writes
                if (st2) {
#pragma unroll
                    for (int j = 0; j < 4; ++j) {
                        fa[j][0] = *reinterpret_cast<const float4*>(
                            af32src[j] + ktn + 64);
                        fa[j][1] = *reinterpret_cast<const float4*>(
                            af32src[j] + ktn + 68);
                    }
                }
            } else {
#pragma unroll
                for (int j = 0; j < 4; ++j) GLD(abfsrc[j] + ktn, nx_ + adst[j]);
            }
        }

#pragma unroll
        for (int kkk = 0; kkk < 2; ++kkk) {
            short8 bfr[NF], af[8];
#pragma unroll
            for (int ni = 0; ni < NF; ++ni) {
                const int br = wn * (NF * 16) + ni * 16 + lrow;
                const int kb = (kkk * 64 + lgrp * 16) ^ ((br & 7) << 4);
                bfr[ni] = *(const short8*)(cu_ + ABYTES + br * 128 + kb);
            }
#pragma unroll
            for (int ml = 0; ml < 8; ++ml) {
                const int ar = wm * 128 + ml * 16 + lrow;
                const int kb = (kkk * 64 + lgrp * 16) ^ ((ar & 7) << 4);
                af[ml] = *(const short8*)(cu_ + ar * 128 + kb);
            }
#pragma unroll
            for (int ml = 0; ml < 8; ++ml)
#pragma unroll
                for (int ni = 0; ni < NF; ++ni)
                    acc[ml][ni] = __builtin_amdgcn_mfma_f32_16x16x32_bf16(
                        bfr[ni], af[ml], acc[ml][ni], 0, 0, 0);
        }

        if (st) {
            // counted wait: retire B(i+1) [+A GLDs on !AFP32]; on AFP32 the
            // 8 fa refill loads (newest) STAY in flight across the barrier.
            if (AFP32 && st2)
                asm volatile("s_waitcnt vmcnt(8) lgkmcnt(0)" ::: "memory");
            else
                asm volatile("s_waitcnt vmcnt(0) lgkmcnt(0)" ::: "memory");
            __builtin_amdgcn_s_barrier();
            asm volatile("" ::: "memory");
        }
    }

    // --- epilogue (swapped operands): lane holds 4 consecutive n at reg r --
    // m = wmoff + mi*16 + lrow ; n = wnoff + ni*16 + lgrp*4 + r
    const int wnoff = n0 + wn * (NF * 16);
    const int wmoff = m0 + wm * 128;
#pragma unroll
    for (int ni = 0; ni < NF; ++ni) {
        const int ncol = wnoff + ni * 16 + lgrp * 4;
        const float4 bv = *reinterpret_cast<const float4*>(&bias[ncol]);
#pragma unroll
        for (int mi = 0; mi < 8; ++mi) {
            const int row = wmoff + mi * 16 + lrow;
            float v0 = acc[mi][ni][0] + bv.x;
            float v1 = acc[mi][ni][1] + bv.y;
            float v2 = acc[mi][ni][2] + bv.z;
            float v3 = acc[mi][ni][3] + bv.w;
            if (RELU) {
                v0 = fmaxf(v0, 0.0f); v1 = fmaxf(v1, 0.0f);
                v2 = fmaxf(v2, 0.0f); v3 = fmaxf(v3, 0.0f);
            }
            const size_t base = (size_t)t * strideC + (size_t)row * N + ncol;
            if (OUTBF16) {
                uint2 p;
                p.x = (uint)f2bf(v0) | ((uint)f2bf(v1) << 16);
                p.y = (uint)f2bf(v2) | ((uint)f2bf(v3) << 16);
                *reinterpret_cast<uint2*>(&((ushort*)Cbase)[base]) = p;
            } else {
                float4 p = {v0, v1, v2, v3};
                *reinterpret_cast<float4*>(&((float*)Cbase)[base]) = p;
            }
        }
    }
}

extern "C" void kernel_launch(void* const* d_in, const int* in_sizes, int n_in,
                              void* d_out, int out_size, void* d_ws, size_t ws_size,
                              hipStream_t stream) {
    const float* x0 = (const float*)d_in[0];
    const float* x1 = (const float*)d_in[1];
    const float* x2 = (const float*)d_in[2];
    const float* x3 = (const float*)d_in[3];
    // d_in[4] = node_type (unused: nodes are blocked by type already)
    const float* W1 = (const float*)d_in[5];
    const float* b1 = (const float*)d_in[6];
    const float* W2[4] = {(const float*)d_in[7], (const float*)d_in[9],
                          (const float*)d_in[11], (const float*)d_in[13]};
    const float* b2[4] = {(const float*)d_in[8], (const float*)d_in[10],
                          (const float*)d_in[12], (const float*)d_in[14]};

    // workspace layout (bytes):
    //   H    bf16 [4][16384][1024]  134217728
    //   W1T  bf16 [4][1024][512]      4194304
    //   W2T  bf16 [4][128][1024]      1048576
    //   b2p  f32  [4][128]                2048
    char* ws = (char*)d_ws;
    ushort* H   = (ushort*)ws;
    ushort* W1T = (ushort*)(ws + 134217728ull);
    ushort* W2T = (ushort*)(ws + 134217728ull + 4194304ull);
    float*  b2p = (float*)(ws + 134217728ull + 4194304ull + 1048576ull);

    // weight conversions (small)
    cvt_w_t_kernel<<<dim3(32, 16, 4), 256, 0, stream>>>(
        W1, W1T, DIN, DH, (size_t)DIN * DH, (size_t)DH * DIN);
    cvt_w2_kernel<<<dim3(4, 32, 4), 256, 0, stream>>>(
        W2[0], W2[1], W2[2], W2[3], b2[0], b2[1], b2[2], b2[3], W2T, b2p);

    // layer 1: H = relu(X @ W1 + b1), fused fp32->bf16 A path, bf16 out
    // grid: 4 types x 64 m-tiles x 4 n-tiles = 1024 (n fastest: A L2 reuse)
    gemmf<256, true, true, true><<<1024, 512, 0, stream>>>(
        x0, x1, x2, x3, W1T, b1, H,
        DH, DIN, NNODE / 256,
        0, (size_t)DH * DIN, (size_t)DH, (size_t)NNODE * DH);

    // layer 2: out = H @ W2 + b2 (padded cols exactly 0), fp32 out
    // grid: 4 types x 64 m-tiles x 1 n-tile = 256
    gemmf<128, false, false, false><<<256, 512, 0, stream>>>(
        H, H, H, H, W2T, b2p, d_out,
        MAXO, DH, NNODE / 256,
        (size_t)NNODE * DH, (size_t)MAXO * DH, (size_t)MAXO,
        (size_t)NNODE * MAXO);
}